// Round 17
// baseline (1104.590 us; speedup 1.0000x reference)
//
#include <hip/hip_runtime.h>
#include <hip/hip_bf16.h>
#include <math.h>

// Problem constants
#define BB 2
#define TT 2048
#define DD 512
#define HH 8
#define HD 64
#define FF 2048
#define VV 32000
#define LL 6
#define MM (BB * TT)   // 4096

typedef unsigned int   u32;
typedef unsigned short u16;
typedef __attribute__((ext_vector_type(8))) short short8;   // bf16x8 frag (4 VGPR)
typedef __attribute__((ext_vector_type(4))) float f32x4;    // acc frag

__device__ __forceinline__ u16 f2bf_bits(float f)
{
    __hip_bfloat16 h = __float2bfloat16(f);   // RNE
    u16 u;
    __builtin_memcpy(&u, &h, 2);
    return u;
}

__device__ __forceinline__ void gll16(const u16* g, u16* l)
{
    __builtin_amdgcn_global_load_lds(
        (const __attribute__((address_space(1))) u32*)g,
        (__attribute__((address_space(3))) u32*)l,
        16, 0, 0);
}

__device__ __forceinline__ float gelu_exact(float v)
{
    return 0.5f * v * (1.0f + erff(v * 0.70710678118654752440f));
}

// XOR-swizzled pointer into a [64][64]-u16 LDS tile (row = 128 B).
__device__ __forceinline__ u16* swp(u16* base, int row, int col)
{
    int off = (row * 128 + col * 2) ^ ((row & 7) << 4);
    return (u16*)((char*)base + off);
}
__device__ __forceinline__ const u16* swpc(const u16* base, int row, int col)
{
    int off = (row * 128 + col * 2) ^ ((row & 7) << 4);
    return (const u16*)((const char*)base + off);
}

// DPP row-rotate max step (16-lane row reduce on the VALU pipe — frees the
// DS pipe that __shfl_xor/ds_swizzle would contend for).
template<int CTRL>
__device__ __forceinline__ float fmax_dpp(float v)
{
    union { float f; int i; } a, b;
    a.f = v;
    b.i = __builtin_amdgcn_mov_dpp(a.i, CTRL, 0xf, 0xf, true);
    return fmaxf(v, b.f);
}

// ---------------------------------------------------------------------------
// Embedding: x[b,t,:] = wte[idx[b,t],:] + wpe[t,:]   (fp32 out)
// ---------------------------------------------------------------------------
__global__ __launch_bounds__(128)
void embed_kernel(const int* __restrict__ idx, const float* __restrict__ wte,
                  const float* __restrict__ wpe, float* __restrict__ x)
{
    int row = blockIdx.x;
    int t = row & (TT - 1);
    int tok = idx[row];
    const float4* wt = (const float4*)(wte + (size_t)tok * DD);
    const float4* wp = (const float4*)(wpe + (size_t)t * DD);
    float4 a = wt[threadIdx.x];
    float4 p = wp[threadIdx.x];
    float4 r;
    r.x = a.x + p.x; r.y = a.y + p.y; r.z = a.z + p.z; r.w = a.w + p.w;
    ((float4*)(x + (size_t)row * DD))[threadIdx.x] = r;
}

// ---------------------------------------------------------------------------
// LayerNorm (fp32 in, bf16 out) — WAVE-PER-ROW: 4 waves/block, one row each;
// lane holds 8 elems (2x float4); reduce via 12 shfl_xor. No LDS, no barrier.
// ---------------------------------------------------------------------------
__global__ __launch_bounds__(256)
void ln_kernel(const float* __restrict__ x, const float* __restrict__ g,
               const float* __restrict__ b, u16* __restrict__ out)
{
    const int wave = threadIdx.x >> 6, lane = threadIdx.x & 63;
    const int row = blockIdx.x * 4 + wave;
    const float* xr = x + (size_t)row * DD;
    const int c = lane * 4;

    float4 v1 = *(const float4*)(xr + c);
    float4 v2 = *(const float4*)(xr + 256 + c);
    float s  = (v1.x + v1.y) + (v1.z + v1.w) + (v2.x + v2.y) + (v2.z + v2.w);
    float ss = v1.x * v1.x + v1.y * v1.y + v1.z * v1.z + v1.w * v1.w
             + v2.x * v2.x + v2.y * v2.y + v2.z * v2.z + v2.w * v2.w;
    #pragma unroll
    for (int o = 32; o; o >>= 1) {
        s  += __shfl_xor(s, o);
        ss += __shfl_xor(ss, o);
    }
    const float mu  = s * (1.0f / DD);
    const float var = ss * (1.0f / DD) - mu * mu;
    const float rs  = rsqrtf(var + 1e-5f);

    float4 g1 = *(const float4*)(g + c);
    float4 b1 = *(const float4*)(b + c);
    float4 g2 = *(const float4*)(g + 256 + c);
    float4 b2 = *(const float4*)(b + 256 + c);

    u16* orow = out + (size_t)row * DD;
    ushort4 o1, o2;
    o1.x = f2bf_bits((v1.x - mu) * rs * g1.x + b1.x);
    o1.y = f2bf_bits((v1.y - mu) * rs * g1.y + b1.y);
    o1.z = f2bf_bits((v1.z - mu) * rs * g1.z + b1.z);
    o1.w = f2bf_bits((v1.w - mu) * rs * g1.w + b1.w);
    o2.x = f2bf_bits((v2.x - mu) * rs * g2.x + b2.x);
    o2.y = f2bf_bits((v2.y - mu) * rs * g2.y + b2.y);
    o2.z = f2bf_bits((v2.z - mu) * rs * g2.z + b2.z);
    o2.w = f2bf_bits((v2.w - mu) * rs * g2.w + b2.w);
    *(ushort4*)(orow + c)       = o1;
    *(ushort4*)(orow + 256 + c) = o2;
}

// ---------------------------------------------------------------------------
// Weight prep: ALL layers' fp32 [K,N] -> bf16 [N,K] transposes + wte->bf16
// flat convert, one launch.
// ---------------------------------------------------------------------------
__global__ __launch_bounds__(256)
void weight_prep_kernel(const float* __restrict__ qkv_w, const float* __restrict__ proj_w,
                        const float* __restrict__ fc1_w, const float* __restrict__ fc2_w,
                        const float* __restrict__ wte,
                        u16* __restrict__ wqa, u16* __restrict__ wpa,
                        u16* __restrict__ w1a, u16* __restrict__ w2a,
                        u16* __restrict__ wteb)
{
    int id = blockIdx.x;
    if (id >= 18432) {
        int i = (id - 18432) * 256 + threadIdx.x;   // < VV*DD/4 = 4,096,000
        float4 v = ((const float4*)wte)[i];
        ushort4 o;
        o.x = f2bf_bits(v.x); o.y = f2bf_bits(v.y);
        o.z = f2bf_bits(v.z); o.w = f2bf_bits(v.w);
        ((ushort4*)wteb)[i] = o;
        return;
    }
    int l = id / 3072, r = id % 3072;
    const float* in; u16* out; int K, N, tt;
    if (r < 768)       { in = qkv_w + (size_t)l * DD * 3 * DD; out = wqa + (size_t)l * 3 * DD * DD; K = DD; N = 3 * DD; tt = r; }
    else if (r < 1024) { in = proj_w + (size_t)l * DD * DD;    out = wpa + (size_t)l * DD * DD;    K = DD; N = DD;     tt = r - 768; }
    else if (r < 2048) { in = fc1_w + (size_t)l * DD * FF;     out = w1a + (size_t)l * DD * FF;    K = DD; N = FF;     tt = r - 1024; }
    else               { in = fc2_w + (size_t)l * FF * DD;     out = w2a + (size_t)l * FF * DD;    K = FF; N = DD;     tt = r - 2048; }
    int ntx = N >> 5;
    int n0 = (tt % ntx) << 5, k0 = (tt / ntx) << 5;
    __shared__ float tile[32][33];
    int tx = threadIdx.x & 31, ty = threadIdx.x >> 5;
    #pragma unroll
    for (int i = 0; i < 4; ++i)
        tile[ty + i * 8][tx] = in[(size_t)(k0 + ty + i * 8) * N + n0 + tx];
    __syncthreads();
    #pragma unroll
    for (int i = 0; i < 4; ++i)
        out[(size_t)(n0 + ty + i * 8) * K + k0 + tx] = f2bf_bits(tile[tx][ty + i * 8]);
}

// ---------------------------------------------------------------------------
// bf16 MFMA GEMM, 2-phase dbuf: C = epi(A @ Bt^T + bias). BN in {128, 64, 32}.
// NMAJOR: n-major XCD decode — each XCD gets a contiguous ~4 MB B-window.
// NTSTORE: non-temporal C stores (C never re-read; keeps B L2-resident).
// QKV_SPLIT: cols [0,1024) -> Cout [M,1024] bf16; cols [1024,1536) ->
// vtb[b, d, t] bf16 (V transposed, t contiguous -> ushort4 store).
// ---------------------------------------------------------------------------
template<int BN, bool GELU_ACT, bool RESID, bool OUTBF16, bool QKV_SPLIT,
         bool NMAJOR = false, bool NTSTORE = false>
__global__ __launch_bounds__(256)
void mfma_gemm(const u16* __restrict__ A, const u16* __restrict__ Bt,
               const float* __restrict__ bias, const float* __restrict__ resid,
               void* __restrict__ Cout, u16* __restrict__ Vout,
               int M, int N, int K)
{
    constexpr int NJ = BN / 32;
    __shared__ u16 As[2][128 * 64];
    __shared__ u16 Bs[2][BN * 64];

    const int tid  = threadIdx.x;
    const int lane = tid & 63;
    const int w    = tid >> 6;
    const int wr   = w >> 1, wc = w & 1;

    const int nbx = gridDim.x;
    const int nwg = nbx * gridDim.y;
    int bid = blockIdx.y * nbx + blockIdx.x;
    int swz = (bid & 7) * (nwg >> 3) + (bid >> 3);
    int m0, n0;
    if constexpr (NMAJOR) {
        m0 = (swz & 31) * 128;        // gridDim.y == 32
        n0 = (swz >> 5) * BN;
    } else {
        m0 = (swz / nbx) * 128;
        n0 = (swz % nbx) * BN;
    }

    const int trow = tid >> 3;
    const int tcol = (tid & 7) * 8;
    const u16* ga = A  + (size_t)(m0 + trow) * K + tcol;
    const u16* gb = Bt + (size_t)(n0 + trow) * K + tcol;

    auto stage = [&](int buf, int k0) {
        u16* la = As[buf] + tid * 8;
        u16* lb = Bs[buf] + tid * 8;
        #pragma unroll
        for (int p = 0; p < 4; ++p)
            gll16(ga + k0 + (size_t)p * 32 * K, la + p * 2048);
        #pragma unroll
        for (int p = 0; p < NJ; ++p)
            gll16(gb + k0 + (size_t)p * 32 * K, lb + p * 2048);
    };

    f32x4 acc[4][NJ] = {};

    const int fr = lane & 15;
    const int fk = (lane >> 4) * 8;

    const int nt = K >> 6;
    stage(0, 0);
    for (int t = 0; t < nt; ++t) {
        asm volatile("s_waitcnt vmcnt(0)" ::: "memory");
        __syncthreads();
        if (t + 1 < nt) stage((t + 1) & 1, (t + 1) << 6);

        const u16* as = As[t & 1];
        const u16* bs = Bs[t & 1];
        #pragma unroll
        for (int ks = 0; ks < 2; ++ks) {
            short8 af[4], bfr[NJ];
            #pragma unroll
            for (int f = 0; f < 4; ++f)
                af[f]  = *(const short8*)&as[(wr * 64 + f * 16 + fr) * 64 + ks * 32 + fk];
            #pragma unroll
            for (int f = 0; f < NJ; ++f)
                bfr[f] = *(const short8*)&bs[(wc * (BN / 2) + f * 16 + fr) * 64 + ks * 32 + fk];
            #pragma unroll
            for (int i = 0; i < 4; ++i)
                #pragma unroll
                for (int j = 0; j < NJ; ++j)
                    acc[i][j] = __builtin_amdgcn_mfma_f32_16x16x32_bf16(
                        af[i], bfr[j], acc[i][j], 0, 0, 0);
        }
    }

    const int c0 = n0 + wc * (BN / 2) + fr;
    const int r0 = m0 + wr * 64 + ((lane >> 4) << 2);
    #pragma unroll
    for (int j = 0; j < NJ; ++j) {
        const int c = c0 + j * 16;
        const float bv = bias ? bias[c] : 0.0f;
        #pragma unroll
        for (int i = 0; i < 4; ++i) {
            const int row0 = r0 + i * 16;
            if constexpr (QKV_SPLIT) {
                if (c < 1024) {
                    #pragma unroll
                    for (int r = 0; r < 4; ++r)
                        ((u16*)Cout)[(size_t)(row0 + r) * 1024 + c] =
                            f2bf_bits(acc[i][j][r] + bv);
                } else {
                    // vtb[(b*512 + (c-1024))*T + t], rows r -> t contiguous
                    ushort4 o;
                    o.x = f2bf_bits(acc[i][j][0] + bv);
                    o.y = f2bf_bits(acc[i][j][1] + bv);
                    o.z = f2bf_bits(acc[i][j][2] + bv);
                    o.w = f2bf_bits(acc[i][j][3] + bv);
                    const int t0 = row0 & (TT - 1);
                    *(ushort4*)&Vout[(((size_t)(row0 >> 11) * 512 + (c - 1024)) << 11) + t0] = o;
                }
            } else {
                #pragma unroll
                for (int r = 0; r < 4; ++r) {
                    const int row = row0 + r;
                    float v = acc[i][j][r] + bv;
                    if constexpr (GELU_ACT) v = gelu_exact(v);
                    if constexpr (RESID) v += resid[(size_t)row * N + c];
                    if constexpr (OUTBF16) {
                        ((u16*)Cout)[(size_t)row * N + c] = f2bf_bits(v);
                    } else if constexpr (NTSTORE) {
                        __builtin_nontemporal_store(v, &((float*)Cout)[(size_t)row * N + c]);
                    } else {
                        ((float*)Cout)[(size_t)row * N + c] = v;
                    }
                }
            }
        }
    }
}

// ---------------------------------------------------------------------------
// bf16 MFMA flash attention (R7 structure) + isolated softmax micro-opts:
//   - DPP row_ror max-reduce (VALU pipe; frees DS pipe)
//   - exact defer-rescale (corr==1 skip when tile max <= running max)
//   - diag-mask hoisted out of the 31/32 non-diagonal tiles
// Everything else identical to the R7/R16 config.
// qkb: bf16 [M,1024] (q at +0, k at +512); vtb: bf16 [B][512][T].
// ---------------------------------------------------------------------------
__global__ __launch_bounds__(256)
void attn_kernel(const u16* __restrict__ qkb, const u16* __restrict__ vtb,
                 u16* __restrict__ y)
{
    const int l = blockIdx.x;
    const int u = l & 255, v = l >> 8;
    const int bh = u & 15;
    const int half = u >> 4;
    const int qt = v ? (16 + half) : (15 - half);
    const int h = bh & (HH - 1);
    const int b = bh >> 3;

    __shared__ alignas(16) u16 Qs[4096];
    __shared__ alignas(16) u16 Ks[2][4096];
    __shared__ alignas(16) u16 Vt[2][4096];   // [d][kv]
    __shared__ alignas(16) u16 Ps[4096];

    const int tid = threadIdx.x;
    const int lane = tid & 63;
    const int w = tid >> 6;
    const int ln = lane & 15, hi = lane >> 4;
    const int q0 = qt * 64;

    const u16* base  = qkb + (size_t)b * TT * 1024 + h * HD;
    const u16* vbase = vtb + (size_t)(b * 512 + h * HD) * TT;

    const int sr = tid >> 2, sc = (tid & 3) * 16;   // staging row/col

    // ---- stage Q (bf16, swizzled) + first K/V tile into regs ----
    {
        const u16* qrow = base + (size_t)(q0 + sr) * 1024;
        *(short8*)swp(Qs, sr, sc)     = *(const short8*)(qrow + sc);
        *(short8*)swp(Qs, sr, sc + 8) = *(const short8*)(qrow + sc + 8);
    }
    short8 rk0, rk1, rv0, rv1;
    {
        const u16* krow = base + (size_t)sr * 1024 + 512;
        rk0 = *(const short8*)(krow + sc);
        rk1 = *(const short8*)(krow + sc + 8);
        const u16* vrow = vbase + (size_t)sr * TT;
        rv0 = *(const short8*)(vrow + sc);
        rv1 = *(const short8*)(vrow + sc + 8);
    }
    __syncthreads();                               // Q visible

    // ---- hoist Q fragments (constant across k-tiles) ----
    short8 aq0 = *(const short8*)swpc(Qs, w * 16 + ln, hi * 8);
    short8 aq1 = *(const short8*)swpc(Qs, w * 16 + ln, 32 + hi * 8);

    const float SC = 0.18033688011112042f;         // 0.125 * log2(e)

    float m[4], lsum[4];
    f32x4 oacc[4] = {};
    #pragma unroll
    for (int r = 0; r < 4; ++r) { m[r] = -INFINITY; lsum[r] = 0.0f; }

    for (int kt = 0; kt <= qt; ++kt) {
        u16* ks = Ks[kt & 1];
        u16* vt = Vt[kt & 1];

        // ---- write staged regs to LDS (vmcnt wait here is a tile old) ----
        *(short8*)swp(ks, sr, sc)     = rk0;
        *(short8*)swp(ks, sr, sc + 8) = rk1;
        *(short8*)swp(vt, sr, sc)     = rv0;
        *(short8*)swp(vt, sr, sc + 8) = rv1;
        __syncthreads();

        // ---- issue next tile's loads (fly during compute below) ----
        if (kt < qt) {
            const int k0n = (kt + 1) * 64;
            const u16* krow = base + (size_t)(k0n + sr) * 1024 + 512;
            rk0 = *(const short8*)(krow + sc);
            rk1 = *(const short8*)(krow + sc + 8);
            const u16* vrow = vbase + (size_t)sr * TT + k0n;
            rv0 = *(const short8*)(vrow + sc);
            rv1 = *(const short8*)(vrow + sc + 8);
        }

        // ---- S = Q K^T ----
        f32x4 sacc[4] = {};
        __builtin_amdgcn_s_setprio(1);
        #pragma unroll
        for (int j = 0; j < 4; ++j) {
            short8 bk0 = *(const short8*)swpc(ks, j * 16 + ln, hi * 8);
            short8 bk1 = *(const short8*)swpc(ks, j * 16 + ln, 32 + hi * 8);
            sacc[j] = __builtin_amdgcn_mfma_f32_16x16x32_bf16(aq0, bk0, sacc[j], 0, 0, 0);
            sacc[j] = __builtin_amdgcn_mfma_f32_16x16x32_bf16(aq1, bk1, sacc[j], 0, 0, 0);
        }
        __builtin_amdgcn_s_setprio(0);

        // ---- online softmax (exp2, DPP max, exact defer-rescale) ----
        const bool diag = (kt == qt);
        #pragma unroll
        for (int r = 0; r < 4; ++r) {
            const int qrow = w * 16 + hi * 4 + r;
            float sv[4];
            #pragma unroll
            for (int j = 0; j < 4; ++j) sv[j] = sacc[j][r] * SC;
            if (diag) {
                #pragma unroll
                for (int j = 0; j < 4; ++j)
                    if (j * 16 + ln > qrow) sv[j] = -INFINITY;
            }
            float rm = fmaxf(fmaxf(sv[0], sv[1]), fmaxf(sv[2], sv[3]));
            rm = fmax_dpp<0x121>(rm);   // row_ror:1
            rm = fmax_dpp<0x122>(rm);   // row_ror:2
            rm = fmax_dpp<0x124>(rm);   // row_ror:4
            rm = fmax_dpp<0x128>(rm);   // row_ror:8
            if (rm > m[r]) {            // corr != 1 only here (exact skip)
                float corr = exp2f(m[r] - rm);
                m[r] = rm;
                lsum[r] *= corr;
                #pragma unroll
                for (int db = 0; db < 4; ++db) oacc[db][r] *= corr;
            }
            const float mn = m[r];
            float p0 = exp2f(sv[0] - mn);
            float p1 = exp2f(sv[1] - mn);
            float p2 = exp2f(sv[2] - mn);
            float p3 = exp2f(sv[3] - mn);
            *swp(Ps, qrow, ln)      = f2bf_bits(p0);
            *swp(Ps, qrow, 16 + ln) = f2bf_bits(p1);
            *swp(Ps, qrow, 32 + ln) = f2bf_bits(p2);
            *swp(Ps, qrow, 48 + ln) = f2bf_bits(p3);
            lsum[r] += (p0 + p1) + (p2 + p3);
        }

        // ---- O += P V (Ps rows are wave-private; no barrier needed) ----
        short8 ap0 = *(const short8*)swpc(Ps, w * 16 + ln, hi * 8);
        short8 ap1 = *(const short8*)swpc(Ps, w * 16 + ln, 32 + hi * 8);
        __builtin_amdgcn_s_setprio(1);
        #pragma unroll
        for (int db = 0; db < 4; ++db) {
            short8 bv0 = *(const short8*)swpc(vt, db * 16 + ln, hi * 8);
            short8 bv1 = *(const short8*)swpc(vt, db * 16 + ln, 32 + hi * 8);
            oacc[db] = __builtin_amdgcn_mfma_f32_16x16x32_bf16(ap0, bv0, oacc[db], 0, 0, 0);
            oacc[db] = __builtin_amdgcn_mfma_f32_16x16x32_bf16(ap1, bv1, oacc[db], 0, 0, 0);
        }
        __builtin_amdgcn_s_setprio(0);
    }

    // ---- epilogue: deferred l-reduction + normalize ----
    #pragma unroll
    for (int r = 0; r < 4; ++r) {
        float lt = lsum[r];
        #pragma unroll
        for (int o = 1; o < 16; o <<= 1) lt += __shfl_xor(lt, o);
        const int q = q0 + w * 16 + hi * 4 + r;
        const float inv = 1.0f / lt;
        u16* yrow = y + (size_t)(b * TT + q) * DD + h * HD;
        #pragma unroll
        for (int db = 0; db < 4; ++db)
            yrow[db * 16 + ln] = f2bf_bits(oacc[db][r] * inv);
    }
}

// ---------------------------------------------------------------------------
// Host-side launch
// ---------------------------------------------------------------------------
extern "C" void kernel_launch(void* const* d_in, const int* in_sizes, int n_in,
                              void* d_out, int out_size, void* d_ws, size_t ws_size,
                              hipStream_t stream)
{
    const int*   idx    = (const int*)  d_in[0];
    const float* wte    = (const float*)d_in[1];
    const float* wpe    = (const float*)d_in[2];
    const float* ln1_g  = (const float*)d_in[3];
    const float* ln1_b  = (const float*)d_in[4];
    const float* qkv_w  = (const float*)d_in[5];
    const float* qkv_b  = (const float*)d_in[6];
    const float* proj_w = (const float*)d_in[7];
    const float* proj_b = (const float*)d_in[8];
    const float* ln2_g  = (const float*)d_in[9];
    const float* ln2_b  = (const float*)d_in[10];
    const float* fc1_w  = (const float*)d_in[11];
    const float* fc1_b  = (const float*)d_in[12];
    const float* fc2_w  = (const float*)d_in[13];
    const float* fc2_b  = (const float*)d_in[14];
    const float* lnf_g  = (const float*)d_in[15];
    const float* lnf_b  = (const float*)d_in[16];
    float* out = (float*)d_out;

    char* ws = (char*)d_ws;
    float* x    = (float*)(ws);                       // [M,D] fp32      8 MB
    u16*   h    = (u16*)(ws + ((size_t)8  << 20));    // [M,D] bf16      4 MB
    u16*   y    = (u16*)(ws + ((size_t)12 << 20));    // [M,D] bf16      4 MB
    u16*   qkb  = (u16*)(ws + ((size_t)16 << 20));    // [M,1024] bf16   8 MB
    u16*   vtb  = (u16*)(ws + ((size_t)24 << 20));    // [B,512,T] bf16  4 MB
    u16*   wqa  = (u16*)(ws + ((size_t)28 << 20));    // 6*[1536,512]    9.4 MB
    u16*   wpa  = (u16*)(ws + ((size_t)38 << 20));    // 6*[512,512]     3.2 MB
    u16*   w1a  = (u16*)(ws + ((size_t)42 << 20));    // 6*[2048,512]   12.6 MB
    u16*   w2a  = (u16*)(ws + ((size_t)55 << 20));    // 6*[512,2048]   12.6 MB
    u16*   ffb  = (u16*)(ws + ((size_t)68 << 20));    // [M,F] bf16     16.8 MB
    u16*   wteb = (u16*)(ws + ((size_t)85 << 20));    // [V,D] bf16     32.8 MB

    embed_kernel<<<MM, 128, 0, stream>>>(idx, wte, wpe, x);

    weight_prep_kernel<<<18432 + 16000, 256, 0, stream>>>(
        qkv_w, proj_w, fc1_w, fc2_w, wte, wqa, wpa, w1a, w2a, wteb);

    for (int l = 0; l < LL; ++l) {
        ln_kernel<<<MM / 4, 256, 0, stream>>>(x, ln1_g + l * DD, ln1_b + l * DD, h);

        mfma_gemm<64, false, false, true, true><<<dim3(24, 32), 256, 0, stream>>>(
            h, wqa + (size_t)l * 3 * DD * DD, qkv_b + (size_t)l * 3 * DD,
            nullptr, qkb, vtb, MM, 3 * DD, DD);

        attn_kernel<<<512, 256, 0, stream>>>(qkb, vtb, y);

        mfma_gemm<32, false, true, false, false><<<dim3(16, 32), 256, 0, stream>>>(
            y, wpa + (size_t)l * DD * DD, proj_b + (size_t)l * DD,
            x, x, nullptr, MM, DD, DD);

        ln_kernel<<<MM / 4, 256, 0, stream>>>(x, ln2_g + l * DD, ln2_b + l * DD, h);

        mfma_gemm<128, true, false, true, false><<<dim3(16, 32), 256, 0, stream>>>(
            h, w1a + (size_t)l * DD * FF, fc1_b + (size_t)l * FF,
            nullptr, ffb, nullptr, MM, FF, DD);

        mfma_gemm<32, false, true, false, false><<<dim3(16, 32), 256, 0, stream>>>(
            ffb, w2a + (size_t)l * FF * DD, fc2_b + (size_t)l * DD,
            x, x, nullptr, MM, DD, FF);
    }

    ln_kernel<<<MM / 4, 256, 0, stream>>>(x, lnf_g, lnf_b, h);

    mfma_gemm<64, false, false, false, false, true, true><<<dim3(500, 32), 256, 0, stream>>>(
        h, wteb, nullptr, nullptr, out, nullptr, MM, VV, DD);
}

// Round 18
// 1084.964 us; speedup vs baseline: 1.0181x; 1.0181x over previous
//
#include <hip/hip_runtime.h>
#include <hip/hip_bf16.h>
#include <math.h>

// Problem constants
#define BB 2
#define TT 2048
#define DD 512
#define HH 8
#define HD 64
#define FF 2048
#define VV 32000
#define LL 6
#define MM (BB * TT)   // 4096

typedef unsigned int   u32;
typedef unsigned short u16;
typedef __attribute__((ext_vector_type(8))) short short8;   // bf16x8 frag (4 VGPR)
typedef __attribute__((ext_vector_type(4))) float f32x4;    // acc frag

__device__ __forceinline__ u16 f2bf_bits(float f)
{
    __hip_bfloat16 h = __float2bfloat16(f);   // RNE
    u16 u;
    __builtin_memcpy(&u, &h, 2);
    return u;
}

__device__ __forceinline__ void gll16(const u16* g, u16* l)
{
    __builtin_amdgcn_global_load_lds(
        (const __attribute__((address_space(1))) u32*)g,
        (__attribute__((address_space(3))) u32*)l,
        16, 0, 0);
}

__device__ __forceinline__ float gelu_exact(float v)
{
    return 0.5f * v * (1.0f + erff(v * 0.70710678118654752440f));
}

// XOR-swizzled pointer into a [64][64]-u16 LDS tile (row = 128 B).
__device__ __forceinline__ u16* swp(u16* base, int row, int col)
{
    int off = (row * 128 + col * 2) ^ ((row & 7) << 4);
    return (u16*)((char*)base + off);
}
__device__ __forceinline__ const u16* swpc(const u16* base, int row, int col)
{
    int off = (row * 128 + col * 2) ^ ((row & 7) << 4);
    return (const u16*)((const char*)base + off);
}

// ---------------------------------------------------------------------------
// Embedding: x[b,t,:] = wte[idx[b,t],:] + wpe[t,:]   (fp32 out)
// ---------------------------------------------------------------------------
__global__ __launch_bounds__(128)
void embed_kernel(const int* __restrict__ idx, const float* __restrict__ wte,
                  const float* __restrict__ wpe, float* __restrict__ x)
{
    int row = blockIdx.x;
    int t = row & (TT - 1);
    int tok = idx[row];
    const float4* wt = (const float4*)(wte + (size_t)tok * DD);
    const float4* wp = (const float4*)(wpe + (size_t)t * DD);
    float4 a = wt[threadIdx.x];
    float4 p = wp[threadIdx.x];
    float4 r;
    r.x = a.x + p.x; r.y = a.y + p.y; r.z = a.z + p.z; r.w = a.w + p.w;
    ((float4*)(x + (size_t)row * DD))[threadIdx.x] = r;
}

// ---------------------------------------------------------------------------
// LayerNorm (fp32 in, bf16 out) — WAVE-PER-ROW: 4 waves/block, one row each;
// lane holds 8 elems (2x float4); reduce via 12 shfl_xor. No LDS, no barrier.
// ---------------------------------------------------------------------------
__global__ __launch_bounds__(256)
void ln_kernel(const float* __restrict__ x, const float* __restrict__ g,
               const float* __restrict__ b, u16* __restrict__ out)
{
    const int wave = threadIdx.x >> 6, lane = threadIdx.x & 63;
    const int row = blockIdx.x * 4 + wave;
    const float* xr = x + (size_t)row * DD;
    const int c = lane * 4;

    float4 v1 = *(const float4*)(xr + c);
    float4 v2 = *(const float4*)(xr + 256 + c);
    float s  = (v1.x + v1.y) + (v1.z + v1.w) + (v2.x + v2.y) + (v2.z + v2.w);
    float ss = v1.x * v1.x + v1.y * v1.y + v1.z * v1.z + v1.w * v1.w
             + v2.x * v2.x + v2.y * v2.y + v2.z * v2.z + v2.w * v2.w;
    #pragma unroll
    for (int o = 32; o; o >>= 1) {
        s  += __shfl_xor(s, o);
        ss += __shfl_xor(ss, o);
    }
    const float mu  = s * (1.0f / DD);
    const float var = ss * (1.0f / DD) - mu * mu;
    const float rs  = rsqrtf(var + 1e-5f);

    float4 g1 = *(const float4*)(g + c);
    float4 b1 = *(const float4*)(b + c);
    float4 g2 = *(const float4*)(g + 256 + c);
    float4 b2 = *(const float4*)(b + 256 + c);

    u16* orow = out + (size_t)row * DD;
    ushort4 o1, o2;
    o1.x = f2bf_bits((v1.x - mu) * rs * g1.x + b1.x);
    o1.y = f2bf_bits((v1.y - mu) * rs * g1.y + b1.y);
    o1.z = f2bf_bits((v1.z - mu) * rs * g1.z + b1.z);
    o1.w = f2bf_bits((v1.w - mu) * rs * g1.w + b1.w);
    o2.x = f2bf_bits((v2.x - mu) * rs * g2.x + b2.x);
    o2.y = f2bf_bits((v2.y - mu) * rs * g2.y + b2.y);
    o2.z = f2bf_bits((v2.z - mu) * rs * g2.z + b2.z);
    o2.w = f2bf_bits((v2.w - mu) * rs * g2.w + b2.w);
    *(ushort4*)(orow + c)       = o1;
    *(ushort4*)(orow + 256 + c) = o2;
}

// ---------------------------------------------------------------------------
// Weight prep: ALL layers' fp32 [K,N] -> bf16 [N,K] transposes + wte->bf16
// flat convert, one launch.
// ---------------------------------------------------------------------------
__global__ __launch_bounds__(256)
void weight_prep_kernel(const float* __restrict__ qkv_w, const float* __restrict__ proj_w,
                        const float* __restrict__ fc1_w, const float* __restrict__ fc2_w,
                        const float* __restrict__ wte,
                        u16* __restrict__ wqa, u16* __restrict__ wpa,
                        u16* __restrict__ w1a, u16* __restrict__ w2a,
                        u16* __restrict__ wteb)
{
    int id = blockIdx.x;
    if (id >= 18432) {
        int i = (id - 18432) * 256 + threadIdx.x;   // < VV*DD/4 = 4,096,000
        float4 v = ((const float4*)wte)[i];
        ushort4 o;
        o.x = f2bf_bits(v.x); o.y = f2bf_bits(v.y);
        o.z = f2bf_bits(v.z); o.w = f2bf_bits(v.w);
        ((ushort4*)wteb)[i] = o;
        return;
    }
    int l = id / 3072, r = id % 3072;
    const float* in; u16* out; int K, N, tt;
    if (r < 768)       { in = qkv_w + (size_t)l * DD * 3 * DD; out = wqa + (size_t)l * 3 * DD * DD; K = DD; N = 3 * DD; tt = r; }
    else if (r < 1024) { in = proj_w + (size_t)l * DD * DD;    out = wpa + (size_t)l * DD * DD;    K = DD; N = DD;     tt = r - 768; }
    else if (r < 2048) { in = fc1_w + (size_t)l * DD * FF;     out = w1a + (size_t)l * DD * FF;    K = DD; N = FF;     tt = r - 1024; }
    else               { in = fc2_w + (size_t)l * FF * DD;     out = w2a + (size_t)l * FF * DD;    K = FF; N = DD;     tt = r - 2048; }
    int ntx = N >> 5;
    int n0 = (tt % ntx) << 5, k0 = (tt / ntx) << 5;
    __shared__ float tile[32][33];
    int tx = threadIdx.x & 31, ty = threadIdx.x >> 5;
    #pragma unroll
    for (int i = 0; i < 4; ++i)
        tile[ty + i * 8][tx] = in[(size_t)(k0 + ty + i * 8) * N + n0 + tx];
    __syncthreads();
    #pragma unroll
    for (int i = 0; i < 4; ++i)
        out[(size_t)(n0 + ty + i * 8) * K + k0 + tx] = f2bf_bits(tile[tx][ty + i * 8]);
}

// ---------------------------------------------------------------------------
// bf16 MFMA GEMM, 2-phase dbuf: C = epi(A @ Bt^T + bias). BN in {128, 64, 32}.
// NMAJOR: n-major XCD decode — each XCD gets a contiguous ~4 MB B-window.
// NTSTORE: non-temporal C stores (C never re-read; keeps B L2-resident).
// QKV_SPLIT: cols [0,1024) -> Cout [M,1024] bf16; cols [1024,1536) ->
// vtb[b, d, t] bf16 (V transposed, t contiguous -> ushort4 store).
// ---------------------------------------------------------------------------
template<int BN, bool GELU_ACT, bool RESID, bool OUTBF16, bool QKV_SPLIT,
         bool NMAJOR = false, bool NTSTORE = false>
__global__ __launch_bounds__(256)
void mfma_gemm(const u16* __restrict__ A, const u16* __restrict__ Bt,
               const float* __restrict__ bias, const float* __restrict__ resid,
               void* __restrict__ Cout, u16* __restrict__ Vout,
               int M, int N, int K)
{
    constexpr int NJ = BN / 32;
    __shared__ u16 As[2][128 * 64];
    __shared__ u16 Bs[2][BN * 64];

    const int tid  = threadIdx.x;
    const int lane = tid & 63;
    const int w    = tid >> 6;
    const int wr   = w >> 1, wc = w & 1;

    const int nbx = gridDim.x;
    const int nwg = nbx * gridDim.y;
    int bid = blockIdx.y * nbx + blockIdx.x;
    int swz = (bid & 7) * (nwg >> 3) + (bid >> 3);
    int m0, n0;
    if constexpr (NMAJOR) {
        m0 = (swz & 31) * 128;        // gridDim.y == 32
        n0 = (swz >> 5) * BN;
    } else {
        m0 = (swz / nbx) * 128;
        n0 = (swz % nbx) * BN;
    }

    const int trow = tid >> 3;
    const int tcol = (tid & 7) * 8;
    const u16* ga = A  + (size_t)(m0 + trow) * K + tcol;
    const u16* gb = Bt + (size_t)(n0 + trow) * K + tcol;

    auto stage = [&](int buf, int k0) {
        u16* la = As[buf] + tid * 8;
        u16* lb = Bs[buf] + tid * 8;
        #pragma unroll
        for (int p = 0; p < 4; ++p)
            gll16(ga + k0 + (size_t)p * 32 * K, la + p * 2048);
        #pragma unroll
        for (int p = 0; p < NJ; ++p)
            gll16(gb + k0 + (size_t)p * 32 * K, lb + p * 2048);
    };

    f32x4 acc[4][NJ] = {};

    const int fr = lane & 15;
    const int fk = (lane >> 4) * 8;

    const int nt = K >> 6;
    stage(0, 0);
    for (int t = 0; t < nt; ++t) {
        asm volatile("s_waitcnt vmcnt(0)" ::: "memory");
        __syncthreads();
        if (t + 1 < nt) stage((t + 1) & 1, (t + 1) << 6);

        const u16* as = As[t & 1];
        const u16* bs = Bs[t & 1];
        #pragma unroll
        for (int ks = 0; ks < 2; ++ks) {
            short8 af[4], bfr[NJ];
            #pragma unroll
            for (int f = 0; f < 4; ++f)
                af[f]  = *(const short8*)&as[(wr * 64 + f * 16 + fr) * 64 + ks * 32 + fk];
            #pragma unroll
            for (int f = 0; f < NJ; ++f)
                bfr[f] = *(const short8*)&bs[(wc * (BN / 2) + f * 16 + fr) * 64 + ks * 32 + fk];
            #pragma unroll
            for (int i = 0; i < 4; ++i)
                #pragma unroll
                for (int j = 0; j < NJ; ++j)
                    acc[i][j] = __builtin_amdgcn_mfma_f32_16x16x32_bf16(
                        af[i], bfr[j], acc[i][j], 0, 0, 0);
        }
    }

    const int c0 = n0 + wc * (BN / 2) + fr;
    const int r0 = m0 + wr * 64 + ((lane >> 4) << 2);
    #pragma unroll
    for (int j = 0; j < NJ; ++j) {
        const int c = c0 + j * 16;
        const float bv = bias ? bias[c] : 0.0f;
        #pragma unroll
        for (int i = 0; i < 4; ++i) {
            const int row0 = r0 + i * 16;
            if constexpr (QKV_SPLIT) {
                if (c < 1024) {
                    #pragma unroll
                    for (int r = 0; r < 4; ++r)
                        ((u16*)Cout)[(size_t)(row0 + r) * 1024 + c] =
                            f2bf_bits(acc[i][j][r] + bv);
                } else {
                    // vtb[(b*512 + (c-1024))*T + t], rows r -> t contiguous
                    ushort4 o;
                    o.x = f2bf_bits(acc[i][j][0] + bv);
                    o.y = f2bf_bits(acc[i][j][1] + bv);
                    o.z = f2bf_bits(acc[i][j][2] + bv);
                    o.w = f2bf_bits(acc[i][j][3] + bv);
                    const int t0 = row0 & (TT - 1);
                    *(ushort4*)&Vout[(((size_t)(row0 >> 11) * 512 + (c - 1024)) << 11) + t0] = o;
                }
            } else {
                #pragma unroll
                for (int r = 0; r < 4; ++r) {
                    const int row = row0 + r;
                    float v = acc[i][j][r] + bv;
                    if constexpr (GELU_ACT) v = gelu_exact(v);
                    if constexpr (RESID) v += resid[(size_t)row * N + c];
                    if constexpr (OUTBF16) {
                        ((u16*)Cout)[(size_t)row * N + c] = f2bf_bits(v);
                    } else if constexpr (NTSTORE) {
                        __builtin_nontemporal_store(v, &((float*)Cout)[(size_t)row * N + c]);
                    } else {
                        ((float*)Cout)[(size_t)row * N + c] = v;
                    }
                }
            }
        }
    }
}

// ---------------------------------------------------------------------------
// bf16 MFMA flash attention, double-buffered K/V + issue-early reg staging.
// Softmax: exp2 domain (scale*log2e folded), per-lane partial row-sums with
// the cross-lane reduce deferred to the epilogue; Q fragments hoisted.
// qkb: bf16 [M,1024] (q at +0, k at +512); vtb: bf16 [B][512][T].
// (Exact R7/R16 config — empirical best. R17's DPP/defer micro-opts
// regressed: divergent defer branch + serial DPP chain cost more than the
// shuffle ops they replaced.)
// ---------------------------------------------------------------------------
__global__ __launch_bounds__(256)
void attn_kernel(const u16* __restrict__ qkb, const u16* __restrict__ vtb,
                 u16* __restrict__ y)
{
    const int l = blockIdx.x;
    const int u = l & 255, v = l >> 8;
    const int bh = u & 15;
    const int half = u >> 4;
    const int qt = v ? (16 + half) : (15 - half);
    const int h = bh & (HH - 1);
    const int b = bh >> 3;

    __shared__ alignas(16) u16 Qs[4096];
    __shared__ alignas(16) u16 Ks[2][4096];
    __shared__ alignas(16) u16 Vt[2][4096];   // [d][kv]
    __shared__ alignas(16) u16 Ps[4096];

    const int tid = threadIdx.x;
    const int lane = tid & 63;
    const int w = tid >> 6;
    const int ln = lane & 15, hi = lane >> 4;
    const int q0 = qt * 64;

    const u16* base  = qkb + (size_t)b * TT * 1024 + h * HD;
    const u16* vbase = vtb + (size_t)(b * 512 + h * HD) * TT;

    const int sr = tid >> 2, sc = (tid & 3) * 16;   // staging row/col

    // ---- stage Q (bf16, swizzled) + first K/V tile into regs ----
    {
        const u16* qrow = base + (size_t)(q0 + sr) * 1024;
        *(short8*)swp(Qs, sr, sc)     = *(const short8*)(qrow + sc);
        *(short8*)swp(Qs, sr, sc + 8) = *(const short8*)(qrow + sc + 8);
    }
    short8 rk0, rk1, rv0, rv1;
    {
        const u16* krow = base + (size_t)sr * 1024 + 512;
        rk0 = *(const short8*)(krow + sc);
        rk1 = *(const short8*)(krow + sc + 8);
        const u16* vrow = vbase + (size_t)sr * TT;
        rv0 = *(const short8*)(vrow + sc);
        rv1 = *(const short8*)(vrow + sc + 8);
    }
    __syncthreads();                               // Q visible

    // ---- hoist Q fragments (constant across k-tiles) ----
    short8 aq0 = *(const short8*)swpc(Qs, w * 16 + ln, hi * 8);
    short8 aq1 = *(const short8*)swpc(Qs, w * 16 + ln, 32 + hi * 8);

    const float SC = 0.18033688011112042f;         // 0.125 * log2(e)

    float m[4], lsum[4];
    f32x4 oacc[4] = {};
    #pragma unroll
    for (int r = 0; r < 4; ++r) { m[r] = -INFINITY; lsum[r] = 0.0f; }

    for (int kt = 0; kt <= qt; ++kt) {
        u16* ks = Ks[kt & 1];
        u16* vt = Vt[kt & 1];

        // ---- write staged regs to LDS (vmcnt wait here is a tile old) ----
        *(short8*)swp(ks, sr, sc)     = rk0;
        *(short8*)swp(ks, sr, sc + 8) = rk1;
        *(short8*)swp(vt, sr, sc)     = rv0;
        *(short8*)swp(vt, sr, sc + 8) = rv1;
        __syncthreads();

        // ---- issue next tile's loads (fly during compute below) ----
        if (kt < qt) {
            const int k0n = (kt + 1) * 64;
            const u16* krow = base + (size_t)(k0n + sr) * 1024 + 512;
            rk0 = *(const short8*)(krow + sc);
            rk1 = *(const short8*)(krow + sc + 8);
            const u16* vrow = vbase + (size_t)sr * TT + k0n;
            rv0 = *(const short8*)(vrow + sc);
            rv1 = *(const short8*)(vrow + sc + 8);
        }

        // ---- S = Q K^T ----
        f32x4 sacc[4] = {};
        __builtin_amdgcn_s_setprio(1);
        #pragma unroll
        for (int j = 0; j < 4; ++j) {
            short8 bk0 = *(const short8*)swpc(ks, j * 16 + ln, hi * 8);
            short8 bk1 = *(const short8*)swpc(ks, j * 16 + ln, 32 + hi * 8);
            sacc[j] = __builtin_amdgcn_mfma_f32_16x16x32_bf16(aq0, bk0, sacc[j], 0, 0, 0);
            sacc[j] = __builtin_amdgcn_mfma_f32_16x16x32_bf16(aq1, bk1, sacc[j], 0, 0, 0);
        }
        __builtin_amdgcn_s_setprio(0);

        // ---- online softmax (exp2 domain, per-lane partial sums) ----
        const bool diag = (kt == qt);
        #pragma unroll
        for (int r = 0; r < 4; ++r) {
            const int qrow = w * 16 + hi * 4 + r;
            float sv[4];
            #pragma unroll
            for (int j = 0; j < 4; ++j) {
                float s = sacc[j][r] * SC;
                if (diag && (j * 16 + ln > qrow)) s = -INFINITY;
                sv[j] = s;
            }
            float rm = fmaxf(fmaxf(sv[0], sv[1]), fmaxf(sv[2], sv[3]));
            #pragma unroll
            for (int o = 1; o < 16; o <<= 1) rm = fmaxf(rm, __shfl_xor(rm, o));
            float mn = fmaxf(m[r], rm);
            float corr = exp2f(m[r] - mn);
            m[r] = mn;
            float p0 = exp2f(sv[0] - mn);
            float p1 = exp2f(sv[1] - mn);
            float p2 = exp2f(sv[2] - mn);
            float p3 = exp2f(sv[3] - mn);
            *swp(Ps, qrow, ln)      = f2bf_bits(p0);
            *swp(Ps, qrow, 16 + ln) = f2bf_bits(p1);
            *swp(Ps, qrow, 32 + ln) = f2bf_bits(p2);
            *swp(Ps, qrow, 48 + ln) = f2bf_bits(p3);
            lsum[r] = lsum[r] * corr + ((p0 + p1) + (p2 + p3));
            #pragma unroll
            for (int db = 0; db < 4; ++db) oacc[db][r] *= corr;
        }

        // ---- O += P V (Ps rows are wave-private; no barrier needed) ----
        short8 ap0 = *(const short8*)swpc(Ps, w * 16 + ln, hi * 8);
        short8 ap1 = *(const short8*)swpc(Ps, w * 16 + ln, 32 + hi * 8);
        __builtin_amdgcn_s_setprio(1);
        #pragma unroll
        for (int db = 0; db < 4; ++db) {
            short8 bv0 = *(const short8*)swpc(vt, db * 16 + ln, hi * 8);
            short8 bv1 = *(const short8*)swpc(vt, db * 16 + ln, 32 + hi * 8);
            oacc[db] = __builtin_amdgcn_mfma_f32_16x16x32_bf16(ap0, bv0, oacc[db], 0, 0, 0);
            oacc[db] = __builtin_amdgcn_mfma_f32_16x16x32_bf16(ap1, bv1, oacc[db], 0, 0, 0);
        }
        __builtin_amdgcn_s_setprio(0);
    }

    // ---- epilogue: deferred l-reduction + normalize ----
    #pragma unroll
    for (int r = 0; r < 4; ++r) {
        float lt = lsum[r];
        #pragma unroll
        for (int o = 1; o < 16; o <<= 1) lt += __shfl_xor(lt, o);
        const int q = q0 + w * 16 + hi * 4 + r;
        const float inv = 1.0f / lt;
        u16* yrow = y + (size_t)(b * TT + q) * DD + h * HD;
        #pragma unroll
        for (int db = 0; db < 4; ++db)
            yrow[db * 16 + ln] = f2bf_bits(oacc[db][r] * inv);
    }
}

// ---------------------------------------------------------------------------
// Host-side launch
// ---------------------------------------------------------------------------
extern "C" void kernel_launch(void* const* d_in, const int* in_sizes, int n_in,
                              void* d_out, int out_size, void* d_ws, size_t ws_size,
                              hipStream_t stream)
{
    const int*   idx    = (const int*)  d_in[0];
    const float* wte    = (const float*)d_in[1];
    const float* wpe    = (const float*)d_in[2];
    const float* ln1_g  = (const float*)d_in[3];
    const float* ln1_b  = (const float*)d_in[4];
    const float* qkv_w  = (const float*)d_in[5];
    const float* qkv_b  = (const float*)d_in[6];
    const float* proj_w = (const float*)d_in[7];
    const float* proj_b = (const float*)d_in[8];
    const float* ln2_g  = (const float*)d_in[9];
    const float* ln2_b  = (const float*)d_in[10];
    const float* fc1_w  = (const float*)d_in[11];
    const float* fc1_b  = (const float*)d_in[12];
    const float* fc2_w  = (const float*)d_in[13];
    const float* fc2_b  = (const float*)d_in[14];
    const float* lnf_g  = (const float*)d_in[15];
    const float* lnf_b  = (const float*)d_in[16];
    float* out = (float*)d_out;

    char* ws = (char*)d_ws;
    float* x    = (float*)(ws);                       // [M,D] fp32      8 MB
    u16*   h    = (u16*)(ws + ((size_t)8  << 20));    // [M,D] bf16      4 MB
    u16*   y    = (u16*)(ws + ((size_t)12 << 20));    // [M,D] bf16      4 MB
    u16*   qkb  = (u16*)(ws + ((size_t)16 << 20));    // [M,1024] bf16   8 MB
    u16*   vtb  = (u16*)(ws + ((size_t)24 << 20));    // [B,512,T] bf16  4 MB
    u16*   wqa  = (u16*)(ws + ((size_t)28 << 20));    // 6*[1536,512]    9.4 MB
    u16*   wpa  = (u16*)(ws + ((size_t)38 << 20));    // 6*[512,512]     3.2 MB
    u16*   w1a  = (u16*)(ws + ((size_t)42 << 20));    // 6*[2048,512]   12.6 MB
    u16*   w2a  = (u16*)(ws + ((size_t)55 << 20));    // 6*[512,2048]   12.6 MB
    u16*   ffb  = (u16*)(ws + ((size_t)68 << 20));    // [M,F] bf16     16.8 MB
    u16*   wteb = (u16*)(ws + ((size_t)85 << 20));    // [V,D] bf16     32.8 MB

    embed_kernel<<<MM, 128, 0, stream>>>(idx, wte, wpe, x);

    weight_prep_kernel<<<18432 + 16000, 256, 0, stream>>>(
        qkv_w, proj_w, fc1_w, fc2_w, wte, wqa, wpa, w1a, w2a, wteb);

    for (int l = 0; l < LL; ++l) {
        ln_kernel<<<MM / 4, 256, 0, stream>>>(x, ln1_g + l * DD, ln1_b + l * DD, h);

        mfma_gemm<64, false, false, true, true><<<dim3(24, 32), 256, 0, stream>>>(
            h, wqa + (size_t)l * 3 * DD * DD, qkv_b + (size_t)l * 3 * DD,
            nullptr, qkb, vtb, MM, 3 * DD, DD);

        attn_kernel<<<512, 256, 0, stream>>>(qkb, vtb, y);

        mfma_gemm<32, false, true, false, false><<<dim3(16, 32), 256, 0, stream>>>(
            y, wpa + (size_t)l * DD * DD, proj_b + (size_t)l * DD,
            x, x, nullptr, MM, DD, DD);

        ln_kernel<<<MM / 4, 256, 0, stream>>>(x, ln2_g + l * DD, ln2_b + l * DD, h);

        mfma_gemm<128, true, false, true, false><<<dim3(16, 32), 256, 0, stream>>>(
            h, w1a + (size_t)l * DD * FF, fc1_b + (size_t)l * FF,
            nullptr, ffb, nullptr, MM, FF, DD);

        mfma_gemm<32, false, true, false, false><<<dim3(16, 32), 256, 0, stream>>>(
            ffb, w2a + (size_t)l * FF * DD, fc2_b + (size_t)l * DD,
            x, x, nullptr, MM, DD, FF);
    }

    ln_kernel<<<MM / 4, 256, 0, stream>>>(x, lnf_g, lnf_b, h);

    mfma_gemm<64, false, false, false, false, true, true><<<dim3(500, 32), 256, 0, stream>>>(
        h, wteb, nullptr, nullptr, out, nullptr, MM, VV, DD);
}